// Round 2
// baseline (662.482 us; speedup 1.0000x reference)
//
#include <hip/hip_runtime.h>

#define H 512
#define W 512
#define NIMG 128
#define TH 16
#define TW 128
#define XR (TH + 6)          // 22 staged rows per tile
#define XC 136               // staged cols: gx = x0-4 .. x0+131
#define XFLAT (XR * XC)      // 2992 floats
#define XPAD 3072            // padded to 3 sweeps of 256 threads * 4 floats
#define YSPLIT 4
#define NT (H / TH / YSPLIT) // 8 y-tiles marched per block

#define YHR_OFF ((long)NIMG * H * W)                      // 33554432
#define BSTRIDE ((long)(H / 2) * (W / 2))                 // 65536
#define YH_SIZE ((long)NIMG * 6 * BSTRIDE)                // 50331648
#define YHI_OFF (YHR_OFF + YH_SIZE)                       // 83886080

__device__ __forceinline__ int reflect512(int g) {
    // symmetric (edge-inclusive) reflection, single fold is enough for |halo|<=4
    g = (g < 0) ? (-1 - g) : g;
    g = (g > H - 1) ? (2 * H - 1 - g) : g;
    return g;
}

__device__ __forceinline__ float4 f4fma(float s, float4 a, float4 acc) {
    acc.x = fmaf(s, a.x, acc.x);
    acc.y = fmaf(s, a.y, acc.y);
    acc.z = fmaf(s, a.z, acc.z);
    acc.w = fmaf(s, a.w, acc.w);
    return acc;
}

__global__ __launch_bounds__(256, 4)
void dtcwt_fwd1(const float* __restrict__ x,
                const float* __restrict__ h0o,
                const float* __restrict__ h1o,
                float* __restrict__ out)
{
    // xin stored FLAT (row r at offset r*XC): staging writes are 3 linear
    // float4 sweeps per thread; P2 indexes [r*XC + c].
    __shared__ __align__(16) float xin[XPAD];
    __shared__ __align__(16) float slo[XR][TW];
    __shared__ __align__(16) float shi[XR][TW];

    const int tid = threadIdx.x;
    const int x0 = blockIdx.x * TW;
    const int ys = blockIdx.y * (NT * TH);   // first output row this block owns
    const int img = blockIdx.z;

    // taps: uniform address -> s_load into SGPRs
    float c0[5], c1[7];
#pragma unroll
    for (int j = 0; j < 5; ++j) c0[j] = h0o[j];
#pragma unroll
    for (int j = 0; j < 7; ++j) c1[j] = h1o[j];

    const long ibase = (long)img * (H * W);
    float* __restrict__ yhr = out + YHR_OFF;
    float* __restrict__ yhi = out + YHI_OFF;
    const float sc = 0.70710678118654752440f;

    // ---- per-thread staging slot precompute (3 float4 slots cover XPAD) ----
    // flat float index f -> row r = f/XC, col c = f%XC, gx = x0 - 4 + c.
    // X-reflection of an aligned out-of-range float4 == reversed in-range float4:
    //   g0 = -4  -> elements reflect to {3,2,1,0}   = reverse(load @ 0)
    //   g0 = 512 -> elements reflect to {511..508}  = reverse(load @ 508)
    int sr[3]; int sst[3]; bool srev[3]; bool sact[3];
#pragma unroll
    for (int s = 0; s < 3; ++s) {
        int flat = tid * 4 + s * 1024;
        sact[s] = (flat < XFLAT);
        int r = flat / XC;
        int c = flat - r * XC;
        int g0 = x0 - 4 + c;
        int st = g0; bool rv = false;
        if (g0 < 0)          { st = -g0 - 4;        rv = true; }
        else if (g0 > W - 4) { st = 2 * W - 4 - g0; rv = true; }
        sr[s] = r; sst[s] = st; srev[s] = rv;
    }

    // issue global loads for tile t (early), write them to LDS (late)
    auto stage_issue = [&](int t, float4 v[3]) {
        const int yb = ys + t * TH - 3;
#pragma unroll
        for (int s = 0; s < 3; ++s) {
            if (!sact[s]) continue;
            const int gy = reflect512(yb + sr[s]);
            v[s] = *(const float4*)&x[ibase + (long)gy * W + sst[s]];
        }
    };
    auto stage_write = [&](float4 v[3]) {
#pragma unroll
        for (int s = 0; s < 3; ++s) {
            if (!sact[s]) continue;
            float4 w = v[s];
            if (srev[s]) w = make_float4(w.w, w.z, w.y, w.x);
            *(float4*)&xin[tid * 4 + s * 1024] = w;
        }
    };

    // ---- prologue: stage tile 0 ----
    {
        float4 stg[3];
        stage_issue(0, stg);
        stage_write(stg);
    }
    __syncthreads();

    for (int t = 0; t < NT; ++t) {
        // ---- issue next tile's loads FIRST: latency hides under P2+P3 ----
        float4 nstg[3];
        if (t + 1 < NT) stage_issue(t + 1, nstg);

        // ---- Phase 2: row filters, float4 in / float4 out ----
        // output w = w0+k (abs x0+w): Lo = sum_j c0[j]*xin[r][w+2+j], Hi = sum_j c1[j]*xin[r][w+1+j]
        for (int i = tid; i < XR * (TW / 4); i += 256) {
            int r = i >> 5;
            int w0 = (i & 31) * 4;
            const float* xr = &xin[r * XC];
            float4 A  = *(const float4*)&xr[w0];
            float4 Bv = *(const float4*)&xr[w0 + 4];
            float4 Cv = *(const float4*)&xr[w0 + 8];
            float f1 = A.y, f2 = A.z, f3 = A.w;
            float f4 = Bv.x, f5 = Bv.y, f6 = Bv.z, f7 = Bv.w;
            float f8 = Cv.x, f9 = Cv.y, f10 = Cv.z;
            float lo0 = c0[0]*f2 + c0[1]*f3 + c0[2]*f4 + c0[3]*f5 + c0[4]*f6;
            float lo1 = c0[0]*f3 + c0[1]*f4 + c0[2]*f5 + c0[3]*f6 + c0[4]*f7;
            float lo2 = c0[0]*f4 + c0[1]*f5 + c0[2]*f6 + c0[3]*f7 + c0[4]*f8;
            float lo3 = c0[0]*f5 + c0[1]*f6 + c0[2]*f7 + c0[3]*f8 + c0[4]*f9;
            float hi0 = c1[0]*f1 + c1[1]*f2 + c1[2]*f3 + c1[3]*f4 + c1[4]*f5 + c1[5]*f6 + c1[6]*f7;
            float hi1 = c1[0]*f2 + c1[1]*f3 + c1[2]*f4 + c1[3]*f5 + c1[4]*f6 + c1[5]*f7 + c1[6]*f8;
            float hi2 = c1[0]*f3 + c1[1]*f4 + c1[2]*f5 + c1[3]*f6 + c1[4]*f7 + c1[5]*f8 + c1[6]*f9;
            float hi3 = c1[0]*f4 + c1[1]*f5 + c1[2]*f6 + c1[3]*f7 + c1[4]*f8 + c1[5]*f9 + c1[6]*f10;
            *(float4*)&slo[r][w0] = make_float4(lo0, lo1, lo2, lo3);
            *(float4*)&shi[r][w0] = make_float4(hi0, hi1, hi2, hi3);
        }
        __syncthreads();

        // ---- Phase 3: column filters + q2c, one thread = 2x4 block (2 quads) ----
        {
            const int qr = tid >> 5;       // 0..7
            const int q4 = tid & 31;       // 0..31
            const int r0 = qr * 2;
            const int w0 = q4 * 4;
            const int yt = ys + t * TH;

            float4 L[8];
#pragma unroll
            for (int j = 0; j < 8; ++j) L[j] = *(const float4*)&slo[r0 + j][w0];

            float4 ll0 = make_float4(0.f, 0.f, 0.f, 0.f);
            float4 ll1 = ll0, lh0 = ll0, lh1 = ll0;
#pragma unroll
            for (int j = 0; j < 5; ++j) {
                ll0 = f4fma(c0[j], L[1 + j], ll0);
                ll1 = f4fma(c0[j], L[2 + j], ll1);
            }
#pragma unroll
            for (int j = 0; j < 7; ++j) {
                lh0 = f4fma(c1[j], L[j],     lh0);
                lh1 = f4fma(c1[j], L[1 + j], lh1);
            }

            const long ylb = ibase + (long)(yt + r0) * W + (x0 + w0);
            *(float4*)&out[ylb]     = ll0;
            *(float4*)&out[ylb + W] = ll1;

            float4 Hv[8];
#pragma unroll
            for (int j = 0; j < 8; ++j) Hv[j] = *(const float4*)&shi[r0 + j][w0];

            float4 hl0 = make_float4(0.f, 0.f, 0.f, 0.f);
            float4 hl1 = hl0, hh0 = hl0, hh1 = hl0;
#pragma unroll
            for (int j = 0; j < 5; ++j) {
                hl0 = f4fma(c0[j], Hv[1 + j], hl0);
                hl1 = f4fma(c0[j], Hv[2 + j], hl1);
            }
#pragma unroll
            for (int j = 0; j < 7; ++j) {
                hh0 = f4fma(c1[j], Hv[j],     hh0);
                hh1 = f4fma(c1[j], Hv[1 + j], hh1);
            }

            // q2c: quadA = (.x,.y), quadB = (.z,.w) of two adjacent quads
            // bands: 0=LoHi.z1 1=HiHi.z1 2=HiLo.z1 3=HiLo.z2 4=HiHi.z2 5=LoHi.z2
            const int qy = (yt >> 1) + qr;
            const int qx = (x0 >> 1) + q4 * 2;
            const long hb = (long)img * 6 * BSTRIDE + (long)qy * (W / 2) + qx;

            *(float2*)&yhr[hb + 0 * BSTRIDE] = make_float2((lh0.x - lh1.y) * sc, (lh0.z - lh1.w) * sc);
            *(float2*)&yhi[hb + 0 * BSTRIDE] = make_float2((lh0.y + lh1.x) * sc, (lh0.w + lh1.z) * sc);
            *(float2*)&yhr[hb + 1 * BSTRIDE] = make_float2((hh0.x - hh1.y) * sc, (hh0.z - hh1.w) * sc);
            *(float2*)&yhi[hb + 1 * BSTRIDE] = make_float2((hh0.y + hh1.x) * sc, (hh0.w + hh1.z) * sc);
            *(float2*)&yhr[hb + 2 * BSTRIDE] = make_float2((hl0.x - hl1.y) * sc, (hl0.z - hl1.w) * sc);
            *(float2*)&yhi[hb + 2 * BSTRIDE] = make_float2((hl0.y + hl1.x) * sc, (hl0.w + hl1.z) * sc);
            *(float2*)&yhr[hb + 3 * BSTRIDE] = make_float2((hl0.x + hl1.y) * sc, (hl0.z + hl1.w) * sc);
            *(float2*)&yhi[hb + 3 * BSTRIDE] = make_float2((hl0.y - hl1.x) * sc, (hl0.w - hl1.z) * sc);
            *(float2*)&yhr[hb + 4 * BSTRIDE] = make_float2((hh0.x + hh1.y) * sc, (hh0.z + hh1.w) * sc);
            *(float2*)&yhi[hb + 4 * BSTRIDE] = make_float2((hh0.y - hh1.x) * sc, (hh0.w - hh1.z) * sc);
            *(float2*)&yhr[hb + 5 * BSTRIDE] = make_float2((lh0.x + lh1.y) * sc, (lh0.z + lh1.w) * sc);
            *(float2*)&yhi[hb + 5 * BSTRIDE] = make_float2((lh0.y - lh1.x) * sc, (lh0.w - lh1.z) * sc);
        }

        // ---- write-late: staged loads arrived long ago; commit to xin ----
        if (t + 1 < NT) stage_write(nstg);
        __syncthreads();
    }
}

extern "C" void kernel_launch(void* const* d_in, const int* in_sizes, int n_in,
                              void* d_out, int out_size, void* d_ws, size_t ws_size,
                              hipStream_t stream) {
    const float* x   = (const float*)d_in[0];
    const float* h0o = (const float*)d_in[1];
    const float* h1o = (const float*)d_in[2];
    float* out = (float*)d_out;
    dim3 grid(W / TW, YSPLIT, NIMG);   // 4 x 4 x 128 = 2048 persistent-ish blocks
    dtcwt_fwd1<<<grid, dim3(256), 0, stream>>>(x, h0o, h1o, out);
}

// Round 3
// 626.578 us; speedup vs baseline: 1.0573x; 1.0573x over previous
//
#include <hip/hip_runtime.h>

#define H 512
#define W 512
#define NIMG 128
#define TH 16
#define TW 128
#define XR (TH + 6)          // 22 staged rows per tile
#define YSPLIT 4
#define NT (H / TH / YSPLIT) // 8 y-tiles marched per block

#define NCHUNK (XR * (TW / 4))   // 704 interior float4 chunks per tile
#define NHALO  (XR * 8)          // 176 halo scalars per tile

#define YHR_OFF ((long)NIMG * H * W)                      // 33554432
#define BSTRIDE ((long)(H / 2) * (W / 2))                 // 65536
#define YH_SIZE ((long)NIMG * 6 * BSTRIDE)                // 50331648
#define YHI_OFF (YHR_OFF + YH_SIZE)                       // 83886080

__device__ __forceinline__ int reflect512(int g) {
    // symmetric (edge-inclusive) reflection, single fold is enough for |halo|<=4
    g = (g < 0) ? (-1 - g) : g;
    g = (g > H - 1) ? (2 * H - 1 - g) : g;
    return g;
}

__device__ __forceinline__ float4 f4fma(float s, float4 a, float4 acc) {
    acc.x = fmaf(s, a.x, acc.x);
    acc.y = fmaf(s, a.y, acc.y);
    acc.z = fmaf(s, a.z, acc.z);
    acc.w = fmaf(s, a.w, acc.w);
    return acc;
}

// async global->LDS, 16B per lane; LDS dest is wave-uniform base + lane*16 (linear)
#define GLOAD_LDS16(g, l) __builtin_amdgcn_global_load_lds(                      \
    (const __attribute__((address_space(1))) void*)(g),                          \
    (__attribute__((address_space(3))) void*)(l), 16, 0, 0)

__global__ __launch_bounds__(256, 4)
void dtcwt_fwd1(const float* __restrict__ x,
                const float* __restrict__ h0o,
                const float* __restrict__ h1o,
                float* __restrict__ out)
{
    // interior staged by global_load_lds (linear dest, in-range gx, no reflect);
    // x-halo (logical cols -4..-1 and 128..131) staged by 1 scalar/thread.
    __shared__ __align__(16) float xint[XR][TW];   // 11.3 KB
    __shared__ __align__(16) float xhalo[XR][8];   // [0..3]=d-4..-1, [4..7]=d128..131
    __shared__ __align__(16) float slo[XR][TW];
    __shared__ __align__(16) float shi[XR][TW];

    const int tid = threadIdx.x;
    const int x0 = blockIdx.x * TW;
    const int ys = blockIdx.y * (NT * TH);   // first output row this block owns
    const int img = blockIdx.z;

    // taps: uniform address -> s_load into SGPRs
    float c0[5], c1[7];
#pragma unroll
    for (int j = 0; j < 5; ++j) c0[j] = h0o[j];
#pragma unroll
    for (int j = 0; j < 7; ++j) c1[j] = h1o[j];

    const long ibase = (long)img * (H * W);
    float* __restrict__ yhr = out + YHR_OFF;
    float* __restrict__ yhi = out + YHI_OFF;
    const float sc = 0.70710678118654752440f;

    // ---- interior staging slots: chunk k = tid + 256*s, k < 704 ----
    // k -> row r = k>>5, c4 = k&31, gx = x0 + 4*c4 (always in [0,508], aligned)
    int   sr[3]; int sgx[3]; bool sact[3]; float* sdst[3];
#pragma unroll
    for (int s = 0; s < 3; ++s) {
        int k = tid + 256 * s;
        sact[s] = (k < NCHUNK);
        sr[s]   = k >> 5;
        sgx[s]  = x0 + 4 * (k & 31);
        sdst[s] = &xint[0][0] + k * 4;
    }
    // ---- halo slot: 176 scalars, row hr, j<4 -> d=-4+j, j>=4 -> d=124+j ----
    const bool hact0 = (tid < NHALO);
    const int  hr = tid >> 3;
    const int  hj = tid & 7;
    const int  hgx = reflect512((hj < 4) ? (x0 - 4 + hj) : (x0 + 124 + hj));

    auto issue_interior = [&](int t) {
        const int yb = ys + t * TH - 3;
#pragma unroll
        for (int s = 0; s < 3; ++s) {
            if (!sact[s]) continue;
            const int gy = reflect512(yb + sr[s]);
            GLOAD_LDS16(&x[ibase + (long)gy * W + sgx[s]], sdst[s]);
        }
    };

    // ---- prologue: stage tile 0 (async interior + scalar halo) ----
    issue_interior(0);
    if (hact0) xhalo[hr][hj] = x[ibase + (long)reflect512(ys - 3 + hr) * W + hgx];
    __syncthreads();   // drains vmcnt (global_load_lds) + lgkm

    for (int t = 0; t < NT; ++t) {
        // early-issue next tile's halo scalar into ONE register (latency hides under P2)
        const bool hact = hact0 && (t + 1 < NT);
        float hreg = 0.f;
        if (hact)
            hreg = x[ibase + (long)reflect512(ys + (t + 1) * TH - 3 + hr) * W + hgx];

        // ---- Phase 2: row filters, float4 in / float4 out ----
        // logical col d relative to x0; output w: Lo=sum c0[j]*X[w-2+j], Hi=sum c1[j]*X[w-3+j]
        for (int i = tid; i < XR * (TW / 4); i += 256) {
            int r = i >> 5;
            int w0 = (i & 31) * 4;
            const float* rowi = &xint[r][0];
            const float* pa = (w0 == 0)   ? &xhalo[r][0] : rowi + (w0 - 4); // d w0-4..w0-1
            const float* pc = (w0 == 124) ? &xhalo[r][4] : rowi + (w0 + 4); // d w0+4..w0+7
            float4 A  = *(const float4*)pa;
            float4 Bv = *(const float4*)(rowi + w0);                        // d w0..w0+3
            float4 Cv = *(const float4*)pc;
            float f1 = A.y, f2 = A.z, f3 = A.w;
            float f4 = Bv.x, f5 = Bv.y, f6 = Bv.z, f7 = Bv.w;
            float f8 = Cv.x, f9 = Cv.y, f10 = Cv.z;
            float lo0 = c0[0]*f2 + c0[1]*f3 + c0[2]*f4 + c0[3]*f5 + c0[4]*f6;
            float lo1 = c0[0]*f3 + c0[1]*f4 + c0[2]*f5 + c0[3]*f6 + c0[4]*f7;
            float lo2 = c0[0]*f4 + c0[1]*f5 + c0[2]*f6 + c0[3]*f7 + c0[4]*f8;
            float lo3 = c0[0]*f5 + c0[1]*f6 + c0[2]*f7 + c0[3]*f8 + c0[4]*f9;
            float hi0 = c1[0]*f1 + c1[1]*f2 + c1[2]*f3 + c1[3]*f4 + c1[4]*f5 + c1[5]*f6 + c1[6]*f7;
            float hi1 = c1[0]*f2 + c1[1]*f3 + c1[2]*f4 + c1[3]*f5 + c1[4]*f6 + c1[5]*f7 + c1[6]*f8;
            float hi2 = c1[0]*f3 + c1[1]*f4 + c1[2]*f5 + c1[3]*f6 + c1[4]*f7 + c1[5]*f8 + c1[6]*f9;
            float hi3 = c1[0]*f4 + c1[1]*f5 + c1[2]*f6 + c1[3]*f7 + c1[4]*f8 + c1[5]*f9 + c1[6]*f10;
            *(float4*)&slo[r][w0] = make_float4(lo0, lo1, lo2, lo3);
            *(float4*)&shi[r][w0] = make_float4(hi0, hi1, hi2, hi3);
        }
        __syncthreads();   // all P2 reads of xint/xhalo complete; slo/shi ready

        // ---- prefetch tile t+1 into xint/xhalo, async; latency hides under P3 ----
        if (t + 1 < NT) {
            issue_interior(t + 1);
            if (hact) xhalo[hr][hj] = hreg;
        }

        // ---- Phase 3: column filters + q2c, one thread = 2x4 block (2 quads) ----
        {
            const int qr = tid >> 5;       // 0..7
            const int q4 = tid & 31;       // 0..31
            const int r0 = qr * 2;
            const int w0 = q4 * 4;
            const int yt = ys + t * TH;

            float4 L[8];
#pragma unroll
            for (int j = 0; j < 8; ++j) L[j] = *(const float4*)&slo[r0 + j][w0];

            float4 ll0 = make_float4(0.f, 0.f, 0.f, 0.f);
            float4 ll1 = ll0, lh0 = ll0, lh1 = ll0;
#pragma unroll
            for (int j = 0; j < 5; ++j) {
                ll0 = f4fma(c0[j], L[1 + j], ll0);
                ll1 = f4fma(c0[j], L[2 + j], ll1);
            }
#pragma unroll
            for (int j = 0; j < 7; ++j) {
                lh0 = f4fma(c1[j], L[j],     lh0);
                lh1 = f4fma(c1[j], L[1 + j], lh1);
            }

            const long ylb = ibase + (long)(yt + r0) * W + (x0 + w0);
            *(float4*)&out[ylb]     = ll0;
            *(float4*)&out[ylb + W] = ll1;

            float4 Hv[8];
#pragma unroll
            for (int j = 0; j < 8; ++j) Hv[j] = *(const float4*)&shi[r0 + j][w0];

            float4 hl0 = make_float4(0.f, 0.f, 0.f, 0.f);
            float4 hl1 = hl0, hh0 = hl0, hh1 = hl0;
#pragma unroll
            for (int j = 0; j < 5; ++j) {
                hl0 = f4fma(c0[j], Hv[1 + j], hl0);
                hl1 = f4fma(c0[j], Hv[2 + j], hl1);
            }
#pragma unroll
            for (int j = 0; j < 7; ++j) {
                hh0 = f4fma(c1[j], Hv[j],     hh0);
                hh1 = f4fma(c1[j], Hv[1 + j], hh1);
            }

            // q2c: quadA = (.x,.y), quadB = (.z,.w) of two adjacent quads
            // bands: 0=LoHi.z1 1=HiHi.z1 2=HiLo.z1 3=HiLo.z2 4=HiHi.z2 5=LoHi.z2
            const int qy = (yt >> 1) + qr;
            const int qx = (x0 >> 1) + q4 * 2;
            const long hb = (long)img * 6 * BSTRIDE + (long)qy * (W / 2) + qx;

            *(float2*)&yhr[hb + 0 * BSTRIDE] = make_float2((lh0.x - lh1.y) * sc, (lh0.z - lh1.w) * sc);
            *(float2*)&yhi[hb + 0 * BSTRIDE] = make_float2((lh0.y + lh1.x) * sc, (lh0.w + lh1.z) * sc);
            *(float2*)&yhr[hb + 1 * BSTRIDE] = make_float2((hh0.x - hh1.y) * sc, (hh0.z - hh1.w) * sc);
            *(float2*)&yhi[hb + 1 * BSTRIDE] = make_float2((hh0.y + hh1.x) * sc, (hh0.w + hh1.z) * sc);
            *(float2*)&yhr[hb + 2 * BSTRIDE] = make_float2((hl0.x - hl1.y) * sc, (hl0.z - hl1.w) * sc);
            *(float2*)&yhi[hb + 2 * BSTRIDE] = make_float2((hl0.y + hl1.x) * sc, (hl0.w + hl1.z) * sc);
            *(float2*)&yhr[hb + 3 * BSTRIDE] = make_float2((hl0.x + hl1.y) * sc, (hl0.z + hl1.w) * sc);
            *(float2*)&yhi[hb + 3 * BSTRIDE] = make_float2((hl0.y - hl1.x) * sc, (hl0.w - hl1.z) * sc);
            *(float2*)&yhr[hb + 4 * BSTRIDE] = make_float2((hh0.x + hh1.y) * sc, (hh0.z + hh1.w) * sc);
            *(float2*)&yhi[hb + 4 * BSTRIDE] = make_float2((hh0.y - hh1.x) * sc, (hh0.w - hh1.z) * sc);
            *(float2*)&yhr[hb + 5 * BSTRIDE] = make_float2((lh0.x + lh1.y) * sc, (lh0.z + lh1.w) * sc);
            *(float2*)&yhi[hb + 5 * BSTRIDE] = make_float2((lh0.y - lh1.x) * sc, (lh0.w - lh1.z) * sc);
        }

        // end-of-iteration barrier: compiler-emitted vmcnt(0)/lgkmcnt(0) drain before
        // s_barrier guarantees the async global_load_lds data landed before next P2.
        __syncthreads();
    }
}

extern "C" void kernel_launch(void* const* d_in, const int* in_sizes, int n_in,
                              void* d_out, int out_size, void* d_ws, size_t ws_size,
                              hipStream_t stream) {
    const float* x   = (const float*)d_in[0];
    const float* h0o = (const float*)d_in[1];
    const float* h1o = (const float*)d_in[2];
    float* out = (float*)d_out;
    dim3 grid(W / TW, YSPLIT, NIMG);   // 4 x 4 x 128 = 2048 blocks
    dtcwt_fwd1<<<grid, dim3(256), 0, stream>>>(x, h0o, h1o, out);
}